// Round 9
// baseline (2599.191 us; speedup 1.0000x reference)
//
#include <hip/hip_runtime.h>
#include <hip/hip_fp16.h>
#include <math.h>

// Liquid-network recurrence, split-K pk_fma, explicit 3-tier weight storage.
// grid=256 (1 batch row/CU), block=512 (8 waves, 2 waves/SIMD, 256 unified regs).
// Thread t = 8g+p: cols [8g,8g+8) over k-slice [64p,64p+64); 3-round DPP
// mirror transpose-reduce lands rec[t] on thread t (validated r5/r8).
// Weights (32 k2-pairs x 8 cols = 256 u32/thread):
//   k2  0..7  -> arch VGPR (64 u32; fits under the observed 124-reg cap)
//   k2  8..22 -> AGPR (120 u32; explicit v_accvgpr_read + v_pk_fma_f16)
//   k2 23..31 -> LDS (18 uint4/thread/step, 147 KB)
// h: f16, single buffer, per-slice rotation swizzle, step-invariant addrs.
// 2 barriers/step. All FMAs are inline-asm v_pk_fma_f16 (guaranteed packed).

#define HID    512
#define NSTEP  1024
#define BLK    512
#define KVR    8                 // k2 pairs in arch VGPRs
#define KAR    15                // k2 pairs in AGPRs
#define KLDS0  (KVR + KAR)       // first LDS k2 (=23)

// LDS byte offsets
#define OFF_WLS  0               // 18 slots x 512 x 16 B = 147456
#define OFF_HB   147456          // 256 u32 = 1024
#define OFF_XLS  148480          // 2048 f32 = 8192
#define OFF_RED  156672          // 16 f32 = 64
#define OFF_HNA  156736          // 512 f32 = 2048
#define OFF_PSUM 158784          // 160 f32 = 640
#define SMEM_BYTES 159424

template <int CTRL>
__device__ __forceinline__ float dpp_f(float v) {
    int r = __builtin_amdgcn_update_dpp(0, __builtin_bit_cast(int, v),
                                        CTRL, 0xF, 0xF, true);
    return __builtin_bit_cast(float, r);
}
// 0xB1 quad_perm xor1, 0x4E quad_perm xor2, 0x1B quad mirror,
// 0x141 row_half_mirror, 0x140 row_mirror.

__device__ __forceinline__ float swz16_f(float v) {
    int r = __builtin_amdgcn_ds_swizzle(__builtin_bit_cast(int, v), 0x401F); // xor16
    return __builtin_bit_cast(float, r);
}
__device__ __forceinline__ uint32_t pack2h(float a, float b) {
    __half2 h2 = __floats2half2_rn(a, b);   // a -> low 16 bits
    union { __half2 h; uint32_t u; } cv; cv.h = h2;
    return cv.u;
}
__device__ __forceinline__ __half2 u2h(uint32_t u) {
    union { uint32_t u; __half2 h; } cv; cv.u = u;
    return cv.h;
}
__device__ __forceinline__ float tanh_fast(float y) {
    float e = __expf(2.0f * y);
    return 1.0f - 2.0f * __builtin_amdgcn_rcpf(e + 1.0f);
}

// packed f16 fma, all-VGPR (VOP3P) — guaranteed single instruction
__device__ __forceinline__ void pkfma(uint32_t& acc, uint32_t w, uint32_t h) {
    asm("v_pk_fma_f16 %0, %1, %2, %0" : "+v"(acc) : "v"(w), "v"(h));
}
// AGPR-resident weight: one explicit full-rate move, then packed fma
__device__ __forceinline__ void pkfma_a(uint32_t& acc, const uint32_t& w_a, uint32_t h) {
    uint32_t tmp;
    asm("v_accvgpr_read_b32 %0, %1" : "=v"(tmp) : "a"(w_a));
    asm("v_pk_fma_f16 %0, %1, %2, %0" : "+v"(acc) : "v"(tmp), "v"(h));
}

extern "C" __global__ void __launch_bounds__(BLK, 2)
__attribute__((amdgpu_waves_per_eu(2, 2)))
liquid_kernel(const float* __restrict__ x, const float* __restrict__ ctx,
              const float* __restrict__ ce_w1, const float* __restrict__ ce_b1,
              const float* __restrict__ ce_w2, const float* __restrict__ ce_b2,
              const float* __restrict__ in_w, const float* __restrict__ in_b,
              const float* __restrict__ rec_w, const float* __restrict__ tau,
              const float* __restrict__ intra_g, const float* __restrict__ intra_b,
              const float* __restrict__ norm_g, const float* __restrict__ norm_b,
              const float* __restrict__ head_w, const float* __restrict__ head_b,
              float* __restrict__ out)
{
    extern __shared__ char smem[];
    uint4*  wls4 = (uint4*)(smem + OFF_WLS);
    float*  xls  = (float*)(smem + OFF_XLS);
    float*  redS = (float*)(smem + OFF_RED);
    float*  hnA  = (float*)(smem + OFF_HNA);
    float*  psum = (float*)(smem + OFF_PSUM);
    char*   hbB  = smem + OFF_HB;
    __half* hbH  = (__half*)hbB;

    const int b  = blockIdx.x;
    const int t  = threadIdx.x;
    const int p  = t & 7;          // k-slice 0..7 (lane bits 0..2)
    const int g  = t >> 3;         // col group 0..63
    const int wv = t >> 6;         // wave id 0..7
    const int ln = t & 63;

    // ---- stage x[b] (8 KB), coalesced ----
    const float* xb = x + (size_t)b * (NSTEP * 2);
    #pragma unroll
    for (int q = 0; q < 4; ++q) xls[t + q * BLK] = xb[t + q * BLK];

    // ---- per-thread params (col t) ----
    const float g_j  = intra_g[t];
    const float bb_j = intra_b[t];
    const float iw0  = in_w[t];
    const float iw1  = in_w[HID + t];
    const float ib_j = in_b[t];
    const float tj   = tau[t];
    const float sp   = (tj > 30.f) ? tj : log1pf(__expf(tj));
    const float itau = 1.0f / sp;

    // ---- h0 = tanh(relu(ctx@ce_w1+b1)@ce_w2+b2) for col t ----
    float t1[32];
    #pragma unroll
    for (int k = 0; k < 32; ++k) {
        float s = ce_b1[k];
        #pragma unroll
        for (int i = 0; i < 6; ++i) s += ctx[b * 6 + i] * ce_w1[i * 32 + k];
        t1[k] = fmaxf(s, 0.f);
    }
    float s0 = ce_b2[t];
    #pragma unroll
    for (int k = 0; k < 32; ++k) s0 += t1[k] * ce_w2[k * HID + t];
    float h = tanh_fast(s0);

    // ---- weights: pair k2 = rows (64p+2k2, +1), cols 8g..8g+7 ----
    uint32_t wreg[KVR * 8];        // arch-VGPR tier
    uint32_t wa[KAR * 8];          // AGPR tier ("a" constraint at use)
    #pragma unroll
    for (int k2 = 0; k2 < KVR; ++k2) {
        const float* pa = rec_w + (size_t)(64 * p + 2 * k2) * HID + 8 * g;
        float4 a0 = *(const float4*)(pa);
        float4 a1 = *(const float4*)(pa + 4);
        float4 b0 = *(const float4*)(pa + HID);
        float4 b1 = *(const float4*)(pa + HID + 4);
        wreg[k2 * 8 + 0] = pack2h(a0.x, b0.x);
        wreg[k2 * 8 + 1] = pack2h(a0.y, b0.y);
        wreg[k2 * 8 + 2] = pack2h(a0.z, b0.z);
        wreg[k2 * 8 + 3] = pack2h(a0.w, b0.w);
        wreg[k2 * 8 + 4] = pack2h(a1.x, b1.x);
        wreg[k2 * 8 + 5] = pack2h(a1.y, b1.y);
        wreg[k2 * 8 + 6] = pack2h(a1.z, b1.z);
        wreg[k2 * 8 + 7] = pack2h(a1.w, b1.w);
    }
    #pragma unroll
    for (int ka = 0; ka < KAR; ++ka) {
        const int k2 = KVR + ka;
        const float* pa = rec_w + (size_t)(64 * p + 2 * k2) * HID + 8 * g;
        float4 a0 = *(const float4*)(pa);
        float4 a1 = *(const float4*)(pa + 4);
        float4 b0 = *(const float4*)(pa + HID);
        float4 b1 = *(const float4*)(pa + HID + 4);
        wa[ka * 8 + 0] = pack2h(a0.x, b0.x);
        wa[ka * 8 + 1] = pack2h(a0.y, b0.y);
        wa[ka * 8 + 2] = pack2h(a0.z, b0.z);
        wa[ka * 8 + 3] = pack2h(a0.w, b0.w);
        wa[ka * 8 + 4] = pack2h(a1.x, b1.x);
        wa[ka * 8 + 5] = pack2h(a1.y, b1.y);
        wa[ka * 8 + 6] = pack2h(a1.z, b1.z);
        wa[ka * 8 + 7] = pack2h(a1.w, b1.w);
    }
    #pragma unroll
    for (int m = 0; m < 32 - KLDS0; ++m) {
        const int k2 = KLDS0 + m;
        const float* pa = rec_w + (size_t)(64 * p + 2 * k2) * HID + 8 * g;
        float4 a0 = *(const float4*)(pa);
        float4 a1 = *(const float4*)(pa + 4);
        float4 b0 = *(const float4*)(pa + HID);
        float4 b1 = *(const float4*)(pa + HID + 4);
        uint4 wA, wB;
        wA.x = pack2h(a0.x, b0.x); wA.y = pack2h(a0.y, b0.y);
        wA.z = pack2h(a0.z, b0.z); wA.w = pack2h(a0.w, b0.w);
        wB.x = pack2h(a1.x, b1.x); wB.y = pack2h(a1.y, b1.y);
        wB.z = pack2h(a1.z, b1.z); wB.w = pack2h(a1.w, b1.w);
        wls4[(2 * m + 0) * BLK + t] = wA;
        wls4[(2 * m + 1) * BLK + t] = wB;
    }

    // ---- h rotation swizzle: logical u32 i=32s+4q+e stored at
    //      j = 32s + 4*((q+s)&7) + e.  Step-invariant write index (col t): ----
    int hwIdx;
    {
        const int sW = t >> 6, qW = (t >> 3) & 7, eW = (t >> 1) & 3;
        const int jW = 32 * sW + 4 * ((qW + sW) & 7) + eW;
        hwIdx = 2 * jW + (t & 1);
    }
    int hAddr[8];
    #pragma unroll
    for (int r = 0; r < 8; ++r) hAddr[r] = 128 * p + 16 * ((r + p) & 7);

    hbH[hwIdx] = __float2half_rn(h);
    __syncthreads();

    for (int step = 0; step < NSTEP; ++step) {
        // ---- pk_fma matvec partials: 8 cols over k-slice [64p,64p+64) ----
        uint32_t acc[8] = {0u, 0u, 0u, 0u, 0u, 0u, 0u, 0u};
        #pragma unroll
        for (int q = 0; q < 8; ++q) {
            uint4 hq = *(const uint4*)(hbB + hAddr[q]);   // logical quad q
            #pragma unroll
            for (int e = 0; e < 4; ++e) {
                const int k2 = 4 * q + e;
                const uint32_t hp = (e == 0) ? hq.x : (e == 1) ? hq.y
                                  : (e == 2) ? hq.z : hq.w;
                if (k2 < KVR) {
                    #pragma unroll
                    for (int c = 0; c < 8; ++c)
                        pkfma(acc[c], wreg[k2 * 8 + c], hp);
                } else if (k2 < KLDS0) {
                    const int ka = k2 - KVR;
                    #pragma unroll
                    for (int c = 0; c < 8; ++c)
                        pkfma_a(acc[c], wa[ka * 8 + c], hp);
                } else {
                    const int m = k2 - KLDS0;
                    uint4 wA = wls4[(2 * m + 0) * BLK + t];
                    uint4 wB = wls4[(2 * m + 1) * BLK + t];
                    pkfma(acc[0], wA.x, hp); pkfma(acc[1], wA.y, hp);
                    pkfma(acc[2], wA.z, hp); pkfma(acc[3], wA.w, hp);
                    pkfma(acc[4], wB.x, hp); pkfma(acc[5], wB.y, hp);
                    pkfma(acc[6], wB.z, hp); pkfma(acc[7], wB.w, hp);
                }
            }
        }
        float fc[8];
        #pragma unroll
        for (int c = 0; c < 8; ++c) {
            __half2 a2 = u2h(acc[c]);
            fc[c] = __low2float(a2) + __high2float(a2);
        }

        // ---- DPP mirror transpose-reduce (validated): rec[t] ----
        float b4[4];
        {
            const bool hi = (p & 4);
            #pragma unroll
            for (int i = 0; i < 4; ++i) {
                float keep = hi ? fc[i + 4] : fc[i];
                float send = hi ? fc[i]     : fc[i + 4];
                b4[i] = keep + dpp_f<0x141>(send);
            }
        }
        float c2[2];
        {
            const bool hi = (p & 2);
            #pragma unroll
            for (int i = 0; i < 2; ++i) {
                float keep = hi ? b4[i + 2] : b4[i];
                float send = hi ? b4[i]     : b4[i + 2];
                c2[i] = keep + dpp_f<0x1B>(send);
            }
        }
        float rec;
        {
            const bool hi = (p & 1);
            float keep = hi ? c2[1] : c2[0];
            float send = hi ? c2[0] : c2[1];
            rec = keep + dpp_f<0xB1>(send);
        }

        float2 xv = ((const float2*)xls)[step];
        float v = fmaf(xv.x, iw0, fmaf(xv.y, iw1, ib_j + rec));

        // ---- LN reduce: 4 DPP + xor16 + xor32 ----
        float s1 = v, sq = v * v;
        s1 += dpp_f<0xB1>(s1);  sq += dpp_f<0xB1>(sq);
        s1 += dpp_f<0x4E>(s1);  sq += dpp_f<0x4E>(sq);
        s1 += dpp_f<0x141>(s1); sq += dpp_f<0x141>(sq);
        s1 += dpp_f<0x140>(s1); sq += dpp_f<0x140>(sq);
        s1 += swz16_f(s1);      sq += swz16_f(sq);
        s1 += __shfl_xor(s1, 32); sq += __shfl_xor(sq, 32);
        if (ln == 0) { redS[wv] = s1; redS[8 + wv] = sq; }
        __syncthreads();   // (1) stats ready; also fences h reads

        const float4* rp = (const float4*)redS;
        float4 r0 = rp[0], r1 = rp[1], r2 = rp[2], r3 = rp[3];
        float S1 = ((r0.x + r0.y) + (r0.z + r0.w)) + ((r1.x + r1.y) + (r1.z + r1.w));
        float S2 = ((r2.x + r2.y) + (r2.z + r2.w)) + ((r3.x + r3.y) + (r3.z + r3.w));
        float mu  = S1 * (1.0f / HID);
        float var = S2 * (1.0f / HID) - mu * mu;
        float rs  = rsqrtf(var + 1e-5f);
        float f   = tanh_fast((v - mu) * rs * g_j + bb_j);

        h = h + (f - h * itau) * 0.1f;
        h = fminf(fmaxf(h, -10.f), 10.f);
        hbH[hwIdx] = __float2half_rn(h);
        __syncthreads();   // (2) h ready
    }

    // ---- final layernorm ----
    float s1 = h, sq = h * h;
    s1 += dpp_f<0xB1>(s1);  sq += dpp_f<0xB1>(sq);
    s1 += dpp_f<0x4E>(s1);  sq += dpp_f<0x4E>(sq);
    s1 += dpp_f<0x141>(s1); sq += dpp_f<0x141>(sq);
    s1 += dpp_f<0x140>(s1); sq += dpp_f<0x140>(sq);
    s1 += swz16_f(s1);      sq += swz16_f(sq);
    s1 += __shfl_xor(s1, 32); sq += __shfl_xor(sq, 32);
    if (ln == 0) { redS[wv] = s1; redS[8 + wv] = sq; }
    __syncthreads();
    {
        const float4* rp = (const float4*)redS;
        float4 r0 = rp[0], r1 = rp[1], r2 = rp[2], r3 = rp[3];
        float S1 = ((r0.x + r0.y) + (r0.z + r0.w)) + ((r1.x + r1.y) + (r1.z + r1.w));
        float S2 = ((r2.x + r2.y) + (r2.z + r2.w)) + ((r3.x + r3.y) + (r3.z + r3.w));
        float mu  = S1 * (1.0f / HID);
        float var = S2 * (1.0f / HID) - mu * mu;
        float rs  = rsqrtf(var + 1e-5f);
        hnA[t] = (h - mu) * rs * norm_g[t] + norm_b[t];
    }
    __syncthreads();

    // ---- heads: out[b, a] = hn . head_w[:, a] + head_b[a] ----
    if (t < 160) {
        int a = t >> 3, part = t & 7;
        float s = 0.f;
        #pragma unroll 8
        for (int q = 0; q < 64; ++q) {
            int row = part * 64 + q;
            s += hnA[row] * head_w[row * 20 + a];
        }
        psum[a * 8 + part] = s;
    }
    __syncthreads();
    if (t < 20) {
        float s = head_b[t];
        #pragma unroll
        for (int q = 0; q < 8; ++q) s += psum[t * 8 + q];
        out[b * 20 + t] = s;
    }
}

extern "C" void kernel_launch(void* const* d_in, const int* in_sizes, int n_in,
                              void* d_out, int out_size, void* d_ws, size_t ws_size,
                              hipStream_t stream) {
    const float* x       = (const float*)d_in[0];
    const float* ctx     = (const float*)d_in[1];
    const float* ce_w1   = (const float*)d_in[2];
    const float* ce_b1   = (const float*)d_in[3];
    const float* ce_w2   = (const float*)d_in[4];
    const float* ce_b2   = (const float*)d_in[5];
    const float* in_w    = (const float*)d_in[6];
    const float* in_b    = (const float*)d_in[7];
    const float* rec_w   = (const float*)d_in[8];
    const float* tau     = (const float*)d_in[9];
    const float* intra_g = (const float*)d_in[10];
    const float* intra_b = (const float*)d_in[11];
    const float* norm_g  = (const float*)d_in[12];
    const float* norm_b  = (const float*)d_in[13];
    const float* head_w  = (const float*)d_in[14];
    const float* head_b  = (const float*)d_in[15];
    float* outp = (float*)d_out;

    (void)d_ws; (void)ws_size; (void)n_in; (void)in_sizes; (void)out_size;

    // opt-in to >64KB dynamic LDS (160 KB/CU on gfx950); host-side, capture-safe
    hipFuncSetAttribute((const void*)liquid_kernel,
                        hipFuncAttributeMaxDynamicSharedMemorySize, SMEM_BYTES);

    liquid_kernel<<<dim3(256), dim3(BLK), SMEM_BYTES, stream>>>(
        x, ctx, ce_w1, ce_b1, ce_w2, ce_b2, in_w, in_b, rec_w, tau,
        intra_g, intra_b, norm_g, norm_b, head_w, head_b, outp);
}